// Round 4
// baseline (395.805 us; speedup 1.0000x reference)
//
#include <hip/hip_runtime.h>
#include <hip/hip_bf16.h>

#define B_ 64
#define N_ 4096
#define KS 8
#define NCH 32          // token chunks (blocks) per batch for attention
#define NG 2            // 16-token groups per wave (tokens/block = 4*NG*16 = 128)
#define TP 136          // padded LDS tile row, bf16 elems (272B row, 16B-aligned)
#define LNEPS 1e-5f
#define EPSA 1e-8f
#define SCALE 0.08838834764831845f   // 1/sqrt(128)

typedef short short8  __attribute__((ext_vector_type(8)));
typedef short short4v __attribute__((ext_vector_type(4)));
typedef float f32x4   __attribute__((ext_vector_type(4)));

__device__ __forceinline__ unsigned short f2bf(float f) {
  union { float f; unsigned u; } v; v.f = f;
  unsigned r = v.u + 0x7fffu + ((v.u >> 16) & 1u);   // RNE
  return (unsigned short)(r >> 16);
}
__device__ __forceinline__ float bflo(unsigned u) {
  union { unsigned u; float f; } c; c.u = u << 16; return c.f;
}
__device__ __forceinline__ float bfhi(unsigned u) {
  union { unsigned u; float f; } c; c.u = u & 0xffff0000u; return c.f;
}
__device__ __forceinline__ float sigmf(float x) { return 1.f / (1.f + __expf(-x)); }

// ---------------- weight prep: combined GRU matrix + transposes ----------------
__global__ __launch_bounds__(256) void prep_weights(
    const float* __restrict__ Wih, const float* __restrict__ Whh,
    const float* __restrict__ Wq,  const float* __restrict__ Wv,
    const float* __restrict__ W1,  const float* __restrict__ W2,
    float* __restrict__ WgT, float* __restrict__ WqT,
    float* __restrict__ WvT, float* __restrict__ W1T, float* __restrict__ W2T)
{
  int id = blockIdx.x * 256 + threadIdx.x;
  if (id < 98304) {
    int d = id / 768, j = id % 768;
    WgT[id] = (j < 384) ? Wih[j*128 + d] : Whh[(j-384)*128 + d];
  } else if (id < 114688) {
    int k = id - 98304; WqT[k] = Wq[(k % 128) * 128 + k / 128];
  } else if (id < 131072) {
    int k = id - 114688; WvT[k] = Wv[(k % 128) * 128 + k / 128];
  } else if (id < 147456) {
    int k = id - 131072; W1T[k] = W1[(k % 128) * 128 + k / 128];
  } else if (id < 163840) {
    int k = id - 147456; W2T[k] = W2[(k % 128) * 128 + k / 128];
  }
}

// ---------------- q~ init from slots_init ----------------
__global__ __launch_bounds__(256) void q_init_kernel(
    const float* __restrict__ slots_in, const float* __restrict__ g_slot, const float* __restrict__ b_slot,
    const float* __restrict__ WqT, const float* __restrict__ bq,
    const float* __restrict__ Wk, const float* __restrict__ bk,
    float* __restrict__ qt, float* __restrict__ qc)
{
  __shared__ float sarr[128];
  __shared__ float qarr[128];
  int row = blockIdx.x, t = threadIdx.x;
  if (t < 64) {
    float a = slots_in[row*128 + t], b = slots_in[row*128 + 64 + t];
    float s = a + b, s2 = a*a + b*b;
    #pragma unroll
    for (int st = 1; st < 64; st <<= 1) { s += __shfl_xor(s, st); s2 += __shfl_xor(s2, st); }
    float mean = s * (1.f/128.f);
    float rstd = rsqrtf(s2 * (1.f/128.f) - mean*mean + LNEPS);
    sarr[t]    = (a - mean) * rstd * g_slot[t]    + b_slot[t];
    sarr[t+64] = (b - mean) * rstd * g_slot[t+64] + b_slot[t+64];
  }
  __syncthreads();
  if (t < 128) {
    float a = bq[t];
    for (int d = 0; d < 128; d++) a += sarr[d] * WqT[d*128 + t];
    qarr[t] = a;
  }
  __syncthreads();
  if (t < 128) {
    float a = 0.f;
    for (int j = 0; j < 128; j++) a += qarr[j] * Wk[j*128 + t];
    qt[row*128 + t] = a * SCALE;
  }
  if (t < 64) {
    float c = qarr[t]*bk[t] + qarr[t+64]*bk[t+64];
    #pragma unroll
    for (int st = 1; st < 64; st <<= 1) c += __shfl_xor(c, st);
    if (t == 0) qc[row] = c * SCALE;
  }
}

// ---------------- standalone LN: x (f32) -> xn (bf16) ----------------
// One-pass: 32 lanes per row, 4 floats/lane (16B loads), 5-stage half-wave
// shfl reduce. Reads x once (134 MB) + writes xn (64 MB) -- removes the
// 134 MB second x pass that made fused attn_ln L3-BW-bound (round-3 finding:
// attn_ln was occupancy-insensitive at ~4 TB/s effective cache-path BW).
__global__ __launch_bounds__(256) void ln_kernel(
    const float* __restrict__ x, const float* __restrict__ g_in, const float* __restrict__ b_in,
    unsigned short* __restrict__ xn)
{
  const int tid = threadIdx.x;
  const int w = tid >> 6, lane = tid & 63;
  const int half = lane >> 5, sl = lane & 31;       // 2 rows per wave per iter
  // block handles 128 consecutive rows; wave w owns rows [w*32, (w+1)*32)
  const size_t row0 = (size_t)blockIdx.x * 128 + w * 32 + half;

  float4 gg = *(const float4*)(g_in + sl*4);
  float4 bb = *(const float4*)(b_in + sl*4);

  for (int i = 0; i < 16; i++) {
    size_t row = row0 + i*2;
    float4 v = *(const float4*)(x + row*128 + sl*4);
    float s  = v.x + v.y + v.z + v.w;
    float s2 = v.x*v.x + v.y*v.y + v.z*v.z + v.w*v.w;
    #pragma unroll
    for (int st = 1; st < 32; st <<= 1) { s += __shfl_xor(s, st); s2 += __shfl_xor(s2, st); }
    float mean = s * (1.f/128.f);
    float rstd = rsqrtf(s2*(1.f/128.f) - mean*mean + LNEPS);
    unsigned short h0 = f2bf((v.x - mean)*rstd*gg.x + bb.x);
    unsigned short h1 = f2bf((v.y - mean)*rstd*gg.y + bb.y);
    unsigned short h2 = f2bf((v.z - mean)*rstd*gg.z + bb.z);
    unsigned short h3 = f2bf((v.w - mean)*rstd*gg.w + bb.w);
    uint2 pk;
    pk.x = (unsigned)h0 | ((unsigned)h1 << 16);
    pk.y = (unsigned)h2 | ((unsigned)h3 << 16);
    *(uint2*)(xn + row*128 + sl*4) = pk;
  }
}

// ---------------- attention sweep (xn bf16 input) ----------------
// grid (NCH=32, B_), 256 threads = 4 waves. Each wave handles NG sequential
// groups of 16 tokens, accumulating U in registers across groups.
__global__ __launch_bounds__(256) void attn_kernel(
    unsigned short* __restrict__ xn,
    const float* __restrict__ qt, const float* __restrict__ qc,
    float* __restrict__ Upart, float* __restrict__ Spart)
{
  __shared__ union ShMem {
    unsigned short xt[4][16][TP];   // 17408 B
    float ured[4][8][128];          // 16384 B
  } sh;
  __shared__ __align__(16) float pb[4][16][8];
  __shared__ float sred[4][8];

  const int tid = threadIdx.x;
  const int w = tid >> 6, lane = tid & 63;
  const int chunk = blockIdx.x, batch = blockIdx.y;
  const int m = lane & 15, quad = lane >> 4;

  // A-fragments: q~ rows (slot = m), zeros for m>=8. A[m][k], k=quad*8+j (+32*kc)
  short8 afrag[4];
  if (m < KS) {
    const float* qp = qt + (batch*KS + m)*128 + quad*8;
    #pragma unroll
    for (int kc = 0; kc < 4; kc++) {
      short8 a;
      #pragma unroll
      for (int j = 0; j < 8; j++) a[j] = (short)f2bf(qp[kc*32 + j]);
      afrag[kc] = a;
    }
  } else {
    #pragma unroll
    for (int kc = 0; kc < 4; kc++) {
      short8 a;
      #pragma unroll
      for (int j = 0; j < 8; j++) a[j] = 0;
      afrag[kc] = a;
    }
  }
  float creg[4];
  #pragma unroll
  for (int r = 0; r < 4; r++) creg[r] = qc[batch*KS + ((quad*4 + r) & 7)];

  // U~ accumulators persist across groups: lane owns dims 2*lane, 2*lane+1
  float u0[8], u1[8];
  #pragma unroll
  for (int i = 0; i < 8; i++) { u0[i] = 0.f; u1[i] = 0.f; }
  float sAcc[4] = {0.f, 0.f, 0.f, 0.f};

  for (int g = 0; g < NG; g++) {
    const int tb = ((chunk*4 + w)*NG + g)*16;

    short8 bfrag[4];
    // direct register B-fragment load: lane (m,quad) = token m, dims quad*8+kc*32
    const unsigned short* xp = xn + (size_t)(batch*N_ + tb + m)*128;
    #pragma unroll
    for (int kc = 0; kc < 4; kc++) {
      bfrag[kc] = *(const short8*)(xp + kc*32 + quad*8);
      *(short8*)&sh.xt[w][m][kc*32 + quad*8] = bfrag[kc];   // mirror for U-pass
    }

    // logits = q~ . xn + c   (D: row=slot(quad*4+r), col=token m)
    f32x4 acc = {0.f, 0.f, 0.f, 0.f};
    #pragma unroll
    for (int kc = 0; kc < 4; kc++)
      acc = __builtin_amdgcn_mfma_f32_16x16x32_bf16(afrag[kc], bfrag[kc], acc, 0, 0, 0);
    float l[4], o[4];
    #pragma unroll
    for (int r = 0; r < 4; r++) l[r] = acc[r] + creg[r];
    #pragma unroll
    for (int r = 0; r < 4; r++) o[r] = __shfl_xor(l[r], 16);   // swap slot halves
    float mx = fmaxf(fmaxf(fmaxf(l[0], l[1]), fmaxf(l[2], l[3])),
                     fmaxf(fmaxf(o[0], o[1]), fmaxf(o[2], o[3])));
    float e0 = __expf(l[0]-mx), e1 = __expf(l[1]-mx), e2 = __expf(l[2]-mx), e3 = __expf(l[3]-mx);
    float den = e0+e1+e2+e3 + __expf(o[0]-mx)+__expf(o[1]-mx)+__expf(o[2]-mx)+__expf(o[3]-mx);
    float rd = 1.f / den;
    float p0 = e0*rd + EPSA, p1 = e1*rd + EPSA, p2 = e2*rd + EPSA, p3 = e3*rd + EPSA;
    if (lane < 32) {   // quads 0/1 hold real slots 0-3 / 4-7 for token m
      float4 pv; pv.x = p0; pv.y = p1; pv.z = p2; pv.w = p3;
      *(float4*)&pb[w][m][quad*4] = pv;
    }

    // U~ accumulate over this group's 16 tokens
    #pragma unroll
    for (int t = 0; t < 16; t++) {
      float4 pA = *(const float4*)&pb[w][t][0];
      float4 pB = *(const float4*)&pb[w][t][4];
      unsigned vp = *(const unsigned*)&sh.xt[w][t][lane*2];
      float f0 = bflo(vp), f1 = bfhi(vp);
      u0[0] += pA.x*f0; u1[0] += pA.x*f1;
      u0[1] += pA.y*f0; u1[1] += pA.y*f1;
      u0[2] += pA.z*f0; u1[2] += pA.z*f1;
      u0[3] += pA.w*f0; u1[3] += pA.w*f1;
      u0[4] += pB.x*f0; u1[4] += pB.x*f1;
      u0[5] += pB.y*f0; u1[5] += pB.y*f1;
      u0[6] += pB.z*f0; u1[6] += pB.z*f1;
      u0[7] += pB.w*f0; u1[7] += pB.w*f1;
    }

    // S: reduce over the 16 token-lanes in each quad-pair, accumulate across groups
    float sac[4] = {p0, p1, p2, p3};
    #pragma unroll
    for (int st = 1; st < 16; st <<= 1) {
      #pragma unroll
      for (int r = 0; r < 4; r++) sac[r] += __shfl_xor(sac[r], st);
    }
    #pragma unroll
    for (int r = 0; r < 4; r++) sAcc[r] += sac[r];
  }

  if (lane == 0)  { sred[w][0]=sAcc[0]; sred[w][1]=sAcc[1]; sred[w][2]=sAcc[2]; sred[w][3]=sAcc[3]; }
  if (lane == 16) { sred[w][4]=sAcc[0]; sred[w][5]=sAcc[1]; sred[w][6]=sAcc[2]; sred[w][7]=sAcc[3]; }

  __syncthreads();                       // xt dead everywhere -> reuse as ured
  #pragma unroll
  for (int i = 0; i < 8; i++)
    *(float2*)&sh.ured[w][i][lane*2] = make_float2(u0[i], u1[i]);
  __syncthreads();

  {
    const float* ur = &sh.ured[0][0][0];
    int i4 = tid * 4;
    float4 a = *(const float4*)(ur + i4);
    float4 b = *(const float4*)(ur + 1024 + i4);
    float4 c = *(const float4*)(ur + 2048 + i4);
    float4 d = *(const float4*)(ur + 3072 + i4);
    float4 o4;
    o4.x = a.x+b.x+c.x+d.x; o4.y = a.y+b.y+c.y+d.y;
    o4.z = a.z+b.z+c.z+d.z; o4.w = a.w+b.w+c.w+d.w;
    *(float4*)(Upart + (size_t)(batch*NCH + chunk)*1024 + i4) = o4;
    if (tid < 8)
      Spart[(batch*NCH + chunk)*8 + tid] =
        sred[0][tid] + sred[1][tid] + sred[2][tid] + sred[3][tid];
  }
}

// ---------------- per-slot-row update: Wv-apply + GRU + MLP + next q~ ----------------
__global__ __launch_bounds__(256) void update_kernel(
    const float* __restrict__ slots_in, float* __restrict__ slots_out,
    const float* __restrict__ Upart, const float* __restrict__ Spart,
    const float* __restrict__ WvT, const float* __restrict__ bv,
    const float* __restrict__ WgT,
    const float* __restrict__ b_ih, const float* __restrict__ b_hh,
    const float* __restrict__ g_mlp, const float* __restrict__ b_mlp,
    const float* __restrict__ W1T, const float* __restrict__ b1,
    const float* __restrict__ W2T, const float* __restrict__ b2,
    const float* __restrict__ g_slot, const float* __restrict__ b_slot,
    const float* __restrict__ WqT, const float* __restrict__ bq,
    const float* __restrict__ Wk, const float* __restrict__ bk,
    float* __restrict__ qt, float* __restrict__ qc)
{
  __shared__ float bu[128], su[128], hb[128];
  __shared__ float gg[768];
  __shared__ float s1[128], smv[128], hmv[128], s2v[128], sqv[128], qa[128];
  __shared__ float up2[2][128];
  __shared__ float stats[2], sSum;
  int row = blockIdx.x, t = threadIdx.x;
  int batch = row >> 3, slot = row & 7;
  const int col = t & 127, hf = t >> 7;

  {  // Upart reduce split over all 256 threads (2 halves of the 32 chunks)
    const float* Up = Upart + ((size_t)(batch*NCH + hf*16)*8 + slot)*128 + col;
    float ua = 0.f;
    #pragma unroll
    for (int c = 0; c < 16; c++) ua += Up[(size_t)c*1024];
    up2[hf][col] = ua;
  }
  if (t < NCH) {
    float sv = Spart[(batch*NCH + t)*8 + slot];
    #pragma unroll
    for (int st = 1; st < NCH; st <<= 1) sv += __shfl_xor(sv, st);
    if (t == 0) sSum = sv;
  }
  if (t >= 64 && t < 192) hb[t-64] = slots_in[row*128 + (t-64)];
  __syncthreads();
  if (t < 128) bu[t] = (up2[0][t] + up2[1][t]) / sSum;
  __syncthreads();
  {  // updates = Wv (U~/S) + bv  -- split gemv
    float a = hf ? 0.f : bv[col];
    const float* W = WvT + hf*64*128;
    const float* v = bu + hf*64;
    #pragma unroll 8
    for (int d = 0; d < 64; d++) a += v[d] * W[d*128 + col];
    __syncthreads();
    up2[hf][col] = a;
  }
  __syncthreads();
  if (t < 128) su[t] = up2[0][t] + up2[1][t];
  __syncthreads();
  {  // GRU gemv: all 256 threads, 3 columns each over combined WgT[128][768]
    float a0 = b_ih[t];
    float a1 = (t < 128) ? b_ih[256+t] : b_hh[t-128];
    float a2 = b_hh[t+128];
    const float* v1p = (t < 128) ? su : hb;
    for (int d = 0; d < 128; d++) {
      float sd = su[d], hd = hb[d], vd = v1p[d];
      const float* wr = WgT + d*768 + t;
      a0 += sd * wr[0];
      a1 += vd * wr[256];
      a2 += hd * wr[512];
    }
    gg[t] = a0; gg[t+256] = a1; gg[t+512] = a2;
  }
  __syncthreads();
  if (t < 128) {                       // GRU gates
    float r = sigmf(gg[t] + gg[384+t]);
    float z = sigmf(gg[128+t] + gg[512+t]);
    float n = tanhf(gg[256+t] + r * gg[640+t]);
    s1[t] = (1.f - z)*n + z*hb[t];
  }
  __syncthreads();
  if (t < 64) {                        // LN(s1) stats (g_mlp)
    float a = s1[t], b = s1[t+64];
    float s = a + b, s2 = a*a + b*b;
    #pragma unroll
    for (int st = 1; st < 64; st <<= 1) { s += __shfl_xor(s, st); s2 += __shfl_xor(s2, st); }
    if (t == 0) { float mean = s*(1.f/128.f); stats[0] = mean;
                  stats[1] = rsqrtf(s2*(1.f/128.f) - mean*mean + LNEPS); }
  }
  __syncthreads();
  if (t < 128) smv[t] = (s1[t] - stats[0])*stats[1]*g_mlp[t] + b_mlp[t];
  __syncthreads();
  {  // h = relu(W1 smv + b1) -- split gemv
    float a = hf ? 0.f : b1[col];
    const float* W = W1T + hf*64*128;
    const float* v = smv + hf*64;
    #pragma unroll 8
    for (int d = 0; d < 64; d++) a += v[d] * W[d*128 + col];
    up2[hf][col] = a;
  }
  __syncthreads();
  if (t < 128) hmv[t] = fmaxf(up2[0][t] + up2[1][t], 0.f);
  __syncthreads();
  {  // s2 = s1 + W2 h + b2 -- split gemv
    float a = 0.f;
    const float* W = W2T + hf*64*128;
    const float* v = hmv + hf*64;
    #pragma unroll 8
    for (int d = 0; d < 64; d++) a += v[d] * W[d*128 + col];
    up2[hf][col] = a;
  }
  __syncthreads();
  if (t < 128) {
    float a = s1[t] + b2[t] + up2[0][t] + up2[1][t];
    s2v[t] = a;
    slots_out[row*128 + t] = a;
  }
  __syncthreads();
  if (t < 64) {                        // LN(new slots) stats (g_slot) for next q
    float a = s2v[t], b = s2v[t+64];
    float s = a + b, s2 = a*a + b*b;
    #pragma unroll
    for (int st = 1; st < 64; st <<= 1) { s += __shfl_xor(s, st); s2 += __shfl_xor(s2, st); }
    if (t == 0) { float mean = s*(1.f/128.f); stats[0] = mean;
                  stats[1] = rsqrtf(s2*(1.f/128.f) - mean*mean + LNEPS); }
  }
  __syncthreads();
  if (t < 128) sqv[t] = (s2v[t] - stats[0])*stats[1]*g_slot[t] + b_slot[t];
  __syncthreads();
  {  // qa = Wq sqv + bq -- split gemv
    float a = hf ? 0.f : bq[col];
    const float* W = WqT + hf*64*128;
    const float* v = sqv + hf*64;
    #pragma unroll 8
    for (int d = 0; d < 64; d++) a += v[d] * W[d*128 + col];
    up2[hf][col] = a;
  }
  __syncthreads();
  if (t < 128) qa[t] = up2[0][t] + up2[1][t];
  __syncthreads();
  {  // q~ = scale * Wk^T qa -- split gemv
    float a = 0.f;
    const float* W = Wk + hf*64*128;
    const float* v = qa + hf*64;
    #pragma unroll 8
    for (int j = 0; j < 64; j++) a += v[j] * W[j*128 + col];
    up2[hf][col] = a;
  }
  __syncthreads();
  if (t < 128) qt[row*128 + t] = (up2[0][t] + up2[1][t]) * SCALE;
  if (t < 64) {
    float c = qa[t]*bk[t] + qa[t+64]*bk[t+64];
    #pragma unroll
    for (int st = 1; st < 64; st <<= 1) c += __shfl_xor(c, st);
    if (t == 0) qc[row] = c * SCALE;
  }
}

extern "C" void kernel_launch(void* const* d_in, const int* in_sizes, int n_in,
                              void* d_out, int out_size, void* d_ws, size_t ws_size,
                              hipStream_t stream) {
  const float* x          = (const float*)d_in[0];
  const float* slots_init = (const float*)d_in[1];
  const float* Wq   = (const float*)d_in[2];
  const float* bq   = (const float*)d_in[3];
  const float* Wk   = (const float*)d_in[4];
  const float* bk   = (const float*)d_in[5];
  const float* Wv   = (const float*)d_in[6];
  const float* bv   = (const float*)d_in[7];
  const float* g_in = (const float*)d_in[8];
  const float* b_in = (const float*)d_in[9];
  const float* g_slot = (const float*)d_in[10];
  const float* b_slot = (const float*)d_in[11];
  const float* g_mlp  = (const float*)d_in[12];
  const float* b_mlp  = (const float*)d_in[13];
  const float* W1   = (const float*)d_in[14];
  const float* b1   = (const float*)d_in[15];
  const float* W2   = (const float*)d_in[16];
  const float* b2   = (const float*)d_in[17];
  const float* Wih  = (const float*)d_in[18];
  const float* Whh  = (const float*)d_in[19];
  const float* b_ih = (const float*)d_in[20];
  const float* b_hh = (const float*)d_in[21];

  char* p = (char*)d_ws;
  unsigned short* xn = (unsigned short*)p; p += (size_t)B_*N_*128*2;   // 64 MB bf16
  float* qt    = (float*)p; p += (size_t)B_*KS*128*4;
  float* qc    = (float*)p; p += (size_t)B_*KS*4 + 2048;               // pad
  float* slots = (float*)p; p += (size_t)B_*KS*128*4;
  float* Upart = (float*)p; p += (size_t)B_*NCH*KS*128*4;              // 8 MB
  float* Spart = (float*)p; p += (size_t)B_*NCH*KS*4 + 2048;
  float* WgT   = (float*)p; p += 98304*4;
  float* WqT   = (float*)p; p += 16384*4;
  float* WvT   = (float*)p; p += 16384*4;
  float* W1T   = (float*)p; p += 16384*4;
  float* W2T   = (float*)p; p += 16384*4;

  prep_weights<<<640, 256, 0, stream>>>(Wih, Whh, Wq, Wv, W1, W2,
                                        WgT, WqT, WvT, W1T, W2T);
  q_init_kernel<<<512, 256, 0, stream>>>(slots_init, g_slot, b_slot, WqT, bq, Wk, bk, qt, qc);

  // LN once: x (f32) -> xn (bf16), one pass over x
  ln_kernel<<<2048, 256, 0, stream>>>(x, g_in, b_in, xn);

  // iteration 0
  attn_kernel<<<dim3(NCH, B_), 256, 0, stream>>>(xn, qt, qc, Upart, Spart);
  update_kernel<<<512, 256, 0, stream>>>(slots_init, slots, Upart, Spart,
      WvT, bv, WgT, b_ih, b_hh, g_mlp, b_mlp, W1T, b1, W2T, b2,
      g_slot, b_slot, WqT, bq, Wk, bk, qt, qc);

  // iteration 1
  attn_kernel<<<dim3(NCH, B_), 256, 0, stream>>>(xn, qt, qc, Upart, Spart);
  update_kernel<<<512, 256, 0, stream>>>(slots, slots, Upart, Spart,
      WvT, bv, WgT, b_ih, b_hh, g_mlp, b_mlp, W1T, b1, W2T, b2,
      g_slot, b_slot, WqT, bq, Wk, bk, qt, qc);

  // iteration 2 (writes d_out)
  attn_kernel<<<dim3(NCH, B_), 256, 0, stream>>>(xn, qt, qc, Upart, Spart);
  update_kernel<<<512, 256, 0, stream>>>(slots, (float*)d_out, Upart, Spart,
      WvT, bv, WgT, b_ih, b_hh, g_mlp, b_mlp, W1T, b1, W2T, b2,
      g_slot, b_slot, WqT, bq, Wk, bk, qt, qc);

  (void)in_sizes; (void)n_in; (void)out_size; (void)ws_size;
}

// Round 5
// 376.951 us; speedup vs baseline: 1.0500x; 1.0500x over previous
//
#include <hip/hip_runtime.h>
#include <hip/hip_bf16.h>

#define B_ 64
#define N_ 4096
#define KS 8
#define NCH 32          // token chunks (blocks) per batch for attention
#define TP 136          // padded LDS tile row, bf16 elems (272B row, 16B-aligned)
#define LNEPS 1e-5f
#define EPSA 1e-8f
#define SCALE 0.08838834764831845f   // 1/sqrt(128)

typedef short short8  __attribute__((ext_vector_type(8)));
typedef short short4v __attribute__((ext_vector_type(4)));
typedef float f32x4   __attribute__((ext_vector_type(4)));
typedef float f32x2   __attribute__((ext_vector_type(2)));

__device__ __forceinline__ unsigned short f2bf(float f) {
  union { float f; unsigned u; } v; v.f = f;
  unsigned r = v.u + 0x7fffu + ((v.u >> 16) & 1u);   // RNE
  return (unsigned short)(r >> 16);
}
__device__ __forceinline__ float bflo(unsigned u) {
  union { unsigned u; float f; } c; c.u = u << 16; return c.f;
}
__device__ __forceinline__ float bfhi(unsigned u) {
  union { unsigned u; float f; } c; c.u = u & 0xffff0000u; return c.f;
}
__device__ __forceinline__ float sigmf(float x) { return 1.f / (1.f + __expf(-x)); }

// packed fp32 FMA: d.lo += f.lo*p, d.hi += f.hi*p, p broadcast from a pair's
// lo or hi word via VOP3P op_sel (CDNA4 v_pk_fma_f32 = the 2x fp32 rate path).
__device__ __forceinline__ void pkfma_lo(f32x2 &d, f32x2 f, f32x2 p2) {
  asm("v_pk_fma_f32 %0, %1, %2, %0 op_sel_hi:[1,0,1]" : "+v"(d) : "v"(f), "v"(p2));
}
__device__ __forceinline__ void pkfma_hi(f32x2 &d, f32x2 f, f32x2 p2) {
  asm("v_pk_fma_f32 %0, %1, %2, %0 op_sel:[0,1,0] op_sel_hi:[1,1,1]" : "+v"(d) : "v"(f), "v"(p2));
}

// ---------------- fused prep: weight transposes + q_init + LN(x)->xn ----------------
// blocks [0,640): weight prep; [640,1152): q_init (row = b-640, raw Wq rows --
// no dependency on prepped WqT); [1152,3200): LN stream (row block = b-1152).
// All three branches independent -> safe in one launch.
__global__ __launch_bounds__(256) void prep_all(
    const float* __restrict__ Wih, const float* __restrict__ Whh,
    const float* __restrict__ Wq,  const float* __restrict__ Wv,
    const float* __restrict__ W1,  const float* __restrict__ W2,
    float* __restrict__ WgT, float* __restrict__ WqT,
    float* __restrict__ WvT, float* __restrict__ W1T, float* __restrict__ W2T,
    const float* __restrict__ slots_in, const float* __restrict__ g_slot, const float* __restrict__ b_slot,
    const float* __restrict__ bq,
    const float* __restrict__ Wk, const float* __restrict__ bk,
    float* __restrict__ qt, float* __restrict__ qc,
    const float* __restrict__ x, const float* __restrict__ g_in, const float* __restrict__ b_in,
    unsigned short* __restrict__ xn)
{
  __shared__ float sarr[128];
  __shared__ float qarr[128];
  const int bb = blockIdx.x, t = threadIdx.x;

  if (bb < 640) {
    int id = bb * 256 + t;
    if (id < 98304) {
      int d = id / 768, j = id % 768;
      WgT[id] = (j < 384) ? Wih[j*128 + d] : Whh[(j-384)*128 + d];
    } else if (id < 114688) {
      int k = id - 98304; WqT[k] = Wq[(k % 128) * 128 + k / 128];
    } else if (id < 131072) {
      int k = id - 114688; WvT[k] = Wv[(k % 128) * 128 + k / 128];
    } else if (id < 147456) {
      int k = id - 131072; W1T[k] = W1[(k % 128) * 128 + k / 128];
    } else if (id < 163840) {
      int k = id - 147456; W2T[k] = W2[(k % 128) * 128 + k / 128];
    }
    return;
  }

  if (bb < 1152) {
    int row = bb - 640;
    if (t < 64) {
      float a = slots_in[row*128 + t], b = slots_in[row*128 + 64 + t];
      float s = a + b, s2 = a*a + b*b;
      #pragma unroll
      for (int st = 1; st < 64; st <<= 1) { s += __shfl_xor(s, st); s2 += __shfl_xor(s2, st); }
      float mean = s * (1.f/128.f);
      float rstd = rsqrtf(s2 * (1.f/128.f) - mean*mean + LNEPS);
      sarr[t]    = (a - mean) * rstd * g_slot[t]    + b_slot[t];
      sarr[t+64] = (b - mean) * rstd * g_slot[t+64] + b_slot[t+64];
    }
    __syncthreads();
    if (t < 128) {                        // q = Wq s + bq  (raw Wq row-dot)
      float a = bq[t];
      for (int d = 0; d < 128; d++) a += sarr[d] * Wq[t*128 + d];
      qarr[t] = a;
    }
    __syncthreads();
    if (t < 128) {
      float a = 0.f;
      for (int j = 0; j < 128; j++) a += qarr[j] * Wk[j*128 + t];
      qt[row*128 + t] = a * SCALE;
    }
    if (t < 64) {
      float c = qarr[t]*bk[t] + qarr[t+64]*bk[t+64];
      #pragma unroll
      for (int st = 1; st < 64; st <<= 1) c += __shfl_xor(c, st);
      if (t == 0) qc[row] = c * SCALE;
    }
    return;
  }

  {  // LN: 32 lanes/row, 4 floats/lane; block handles 128 rows
    const int w = t >> 6, lane = t & 63;
    const int half = lane >> 5, sl = lane & 31;
    const size_t row0 = (size_t)(bb - 1152) * 128 + w * 32 + half;
    float4 gg = *(const float4*)(g_in + sl*4);
    float4 bv4 = *(const float4*)(b_in + sl*4);
    for (int i = 0; i < 16; i++) {
      size_t row = row0 + i*2;
      float4 v = *(const float4*)(x + row*128 + sl*4);
      float s  = v.x + v.y + v.z + v.w;
      float s2 = v.x*v.x + v.y*v.y + v.z*v.z + v.w*v.w;
      #pragma unroll
      for (int st = 1; st < 32; st <<= 1) { s += __shfl_xor(s, st); s2 += __shfl_xor(s2, st); }
      float mean = s * (1.f/128.f);
      float rstd = rsqrtf(s2*(1.f/128.f) - mean*mean + LNEPS);
      unsigned short h0 = f2bf((v.x - mean)*rstd*gg.x + bv4.x);
      unsigned short h1 = f2bf((v.y - mean)*rstd*gg.y + bv4.y);
      unsigned short h2 = f2bf((v.z - mean)*rstd*gg.z + bv4.z);
      unsigned short h3 = f2bf((v.w - mean)*rstd*gg.w + bv4.w);
      uint2 pk;
      pk.x = (unsigned)h0 | ((unsigned)h1 << 16);
      pk.y = (unsigned)h2 | ((unsigned)h3 << 16);
      *(uint2*)(xn + row*128 + sl*4) = pk;
    }
  }
}

// ---------------- attention sweep (xn bf16 input) ----------------
// grid (NCH=32, B_), 256 threads = 4 waves, 32 tokens/wave (2 groups of 16).
// All 8 global B-fragment loads hoisted to kernel start (both groups) so the
// HBM/L3 latency is paid once, up front. U-pass uses v_pk_fma_f32 (packed
// 2xfp32) -- halves the dominant VALU instruction count vs scalar fmac with
// bit-identical results (same accumulation order, fma precision).
__global__ __launch_bounds__(256) void attn_kernel(
    const unsigned short* __restrict__ xn,
    const float* __restrict__ qt, const float* __restrict__ qc,
    float* __restrict__ Upart, float* __restrict__ Spart)
{
  __shared__ union ShMem {
    unsigned short xt[4][16][TP];   // 17408 B (per-group tile, reused)
    float ured[4][8][128];          // 16384 B
  } sh;
  __shared__ __align__(16) float pb[4][16][8];
  __shared__ float sred[4][8];

  const int tid = threadIdx.x;
  const int w = tid >> 6, lane = tid & 63;
  const int chunk = blockIdx.x, batch = blockIdx.y;
  const int m = lane & 15, quad = lane >> 4;

  // A-fragments: q~ rows (slot = m), zeros for m>=8. A[m][k], k=quad*8+j (+32*kc)
  short8 afrag[4];
  if (m < KS) {
    const float* qp = qt + (batch*KS + m)*128 + quad*8;
    #pragma unroll
    for (int kc = 0; kc < 4; kc++) {
      short8 a;
      #pragma unroll
      for (int j = 0; j < 8; j++) a[j] = (short)f2bf(qp[kc*32 + j]);
      afrag[kc] = a;
    }
  } else {
    #pragma unroll
    for (int kc = 0; kc < 4; kc++) {
      short8 a;
      #pragma unroll
      for (int j = 0; j < 8; j++) a[j] = 0;
      afrag[kc] = a;
    }
  }
  float creg[4];
  #pragma unroll
  for (int r = 0; r < 4; r++) creg[r] = qc[batch*KS + ((quad*4 + r) & 7)];

  // hoisted B-fragment loads for BOTH 16-token groups (8 independent loads)
  const int tb = (chunk*4 + w) * 32;
  const unsigned short* xp0 = xn + (size_t)(batch*N_ + tb + m)*128;
  const unsigned short* xp1 = xp0 + 16*128;
  short8 bfA[4], bfB[4];
  #pragma unroll
  for (int kc = 0; kc < 4; kc++) bfA[kc] = *(const short8*)(xp0 + kc*32 + quad*8);
  #pragma unroll
  for (int kc = 0; kc < 4; kc++) bfB[kc] = *(const short8*)(xp1 + kc*32 + quad*8);

  // U~ accumulators: lane owns dims 2*lane, 2*lane+1 as one packed pair
  f32x2 u01[8];
  #pragma unroll
  for (int i = 0; i < 8; i++) { u01[i].x = 0.f; u01[i].y = 0.f; }
  float sAcc[4] = {0.f, 0.f, 0.f, 0.f};

  #pragma unroll
  for (int g = 0; g < 2; g++) {
    short8* bf = g ? bfB : bfA;

    // stage this group's tile in LDS (per-wave, wave-ordered vs reads below)
    #pragma unroll
    for (int kc = 0; kc < 4; kc++)
      *(short8*)&sh.xt[w][m][kc*32 + quad*8] = bf[kc];

    // logits = q~ . xn + c   (D: row=slot(quad*4+r), col=token m)
    f32x4 acc = {0.f, 0.f, 0.f, 0.f};
    #pragma unroll
    for (int kc = 0; kc < 4; kc++)
      acc = __builtin_amdgcn_mfma_f32_16x16x32_bf16(afrag[kc], bf[kc], acc, 0, 0, 0);
    float l[4], o[4];
    #pragma unroll
    for (int r = 0; r < 4; r++) l[r] = acc[r] + creg[r];
    #pragma unroll
    for (int r = 0; r < 4; r++) o[r] = __shfl_xor(l[r], 16);   // swap slot halves
    float mx = fmaxf(fmaxf(fmaxf(l[0], l[1]), fmaxf(l[2], l[3])),
                     fmaxf(fmaxf(o[0], o[1]), fmaxf(o[2], o[3])));
    float e0 = __expf(l[0]-mx), e1 = __expf(l[1]-mx), e2 = __expf(l[2]-mx), e3 = __expf(l[3]-mx);
    float den = e0+e1+e2+e3 + __expf(o[0]-mx)+__expf(o[1]-mx)+__expf(o[2]-mx)+__expf(o[3]-mx);
    float rd = 1.f / den;
    float p0 = e0*rd + EPSA, p1 = e1*rd + EPSA, p2 = e2*rd + EPSA, p3 = e3*rd + EPSA;
    if (lane < 32) {   // quads 0/1 hold real slots 0-3 / 4-7 for token m
      float4 pv; pv.x = p0; pv.y = p1; pv.z = p2; pv.w = p3;
      *(float4*)&pb[w][m][quad*4] = pv;
    }

    // U~ accumulate over this group's 16 tokens (packed fp32 FMA)
    #pragma unroll
    for (int t = 0; t < 16; t++) {
      f32x2 pA01 = *(const f32x2*)&pb[w][t][0];
      f32x2 pA23 = *(const f32x2*)&pb[w][t][2];
      f32x2 pB01 = *(const f32x2*)&pb[w][t][4];
      f32x2 pB23 = *(const f32x2*)&pb[w][t][6];
      unsigned vp = *(const unsigned*)&sh.xt[w][t][lane*2];
      f32x2 f; f.x = bflo(vp); f.y = bfhi(vp);
      pkfma_lo(u01[0], f, pA01); pkfma_hi(u01[1], f, pA01);
      pkfma_lo(u01[2], f, pA23); pkfma_hi(u01[3], f, pA23);
      pkfma_lo(u01[4], f, pB01); pkfma_hi(u01[5], f, pB01);
      pkfma_lo(u01[6], f, pB23); pkfma_hi(u01[7], f, pB23);
    }

    // S: reduce over the 16 token-lanes in each quad-pair, accumulate across groups
    float sac[4] = {p0, p1, p2, p3};
    #pragma unroll
    for (int st = 1; st < 16; st <<= 1) {
      #pragma unroll
      for (int r = 0; r < 4; r++) sac[r] += __shfl_xor(sac[r], st);
    }
    #pragma unroll
    for (int r = 0; r < 4; r++) sAcc[r] += sac[r];
  }

  if (lane == 0)  { sred[w][0]=sAcc[0]; sred[w][1]=sAcc[1]; sred[w][2]=sAcc[2]; sred[w][3]=sAcc[3]; }
  if (lane == 16) { sred[w][4]=sAcc[0]; sred[w][5]=sAcc[1]; sred[w][6]=sAcc[2]; sred[w][7]=sAcc[3]; }

  __syncthreads();                       // xt dead everywhere -> reuse as ured
  #pragma unroll
  for (int i = 0; i < 8; i++)
    *(f32x2*)&sh.ured[w][i][lane*2] = u01[i];
  __syncthreads();

  {
    const float* ur = &sh.ured[0][0][0];
    int i4 = tid * 4;
    float4 a = *(const float4*)(ur + i4);
    float4 b = *(const float4*)(ur + 1024 + i4);
    float4 c = *(const float4*)(ur + 2048 + i4);
    float4 d = *(const float4*)(ur + 3072 + i4);
    float4 o4;
    o4.x = a.x+b.x+c.x+d.x; o4.y = a.y+b.y+c.y+d.y;
    o4.z = a.z+b.z+c.z+d.z; o4.w = a.w+b.w+c.w+d.w;
    *(float4*)(Upart + (size_t)(batch*NCH + chunk)*1024 + i4) = o4;
    if (tid < 8)
      Spart[(batch*NCH + chunk)*8 + tid] =
        sred[0][tid] + sred[1][tid] + sred[2][tid] + sred[3][tid];
  }
}

// ---------------- per-slot-row update: Wv-apply + GRU + MLP + next q~ ----------------
__global__ __launch_bounds__(256) void update_kernel(
    const float* __restrict__ slots_in, float* __restrict__ slots_out,
    const float* __restrict__ Upart, const float* __restrict__ Spart,
    const float* __restrict__ WvT, const float* __restrict__ bv,
    const float* __restrict__ WgT,
    const float* __restrict__ b_ih, const float* __restrict__ b_hh,
    const float* __restrict__ g_mlp, const float* __restrict__ b_mlp,
    const float* __restrict__ W1T, const float* __restrict__ b1,
    const float* __restrict__ W2T, const float* __restrict__ b2,
    const float* __restrict__ g_slot, const float* __restrict__ b_slot,
    const float* __restrict__ WqT, const float* __restrict__ bq,
    const float* __restrict__ Wk, const float* __restrict__ bk,
    float* __restrict__ qt, float* __restrict__ qc)
{
  __shared__ float bu[128], su[128], hb[128];
  __shared__ float gg[768];
  __shared__ float s1[128], smv[128], hmv[128], s2v[128], sqv[128], qa[128];
  __shared__ float up2[2][128];
  __shared__ float stats[2], sSum;
  int row = blockIdx.x, t = threadIdx.x;
  int batch = row >> 3, slot = row & 7;
  const int col = t & 127, hf = t >> 7;

  {  // Upart reduce split over all 256 threads (2 halves of the 32 chunks)
    const float* Up = Upart + ((size_t)(batch*NCH + hf*16)*8 + slot)*128 + col;
    float ua = 0.f;
    #pragma unroll
    for (int c = 0; c < 16; c++) ua += Up[(size_t)c*1024];
    up2[hf][col] = ua;
  }
  if (t < NCH) {
    float sv = Spart[(batch*NCH + t)*8 + slot];
    #pragma unroll
    for (int st = 1; st < NCH; st <<= 1) sv += __shfl_xor(sv, st);
    if (t == 0) sSum = sv;
  }
  if (t >= 64 && t < 192) hb[t-64] = slots_in[row*128 + (t-64)];
  __syncthreads();
  if (t < 128) bu[t] = (up2[0][t] + up2[1][t]) / sSum;
  __syncthreads();
  {  // updates = Wv (U~/S) + bv  -- split gemv
    float a = hf ? 0.f : bv[col];
    const float* W = WvT + hf*64*128;
    const float* v = bu + hf*64;
    #pragma unroll 8
    for (int d = 0; d < 64; d++) a += v[d] * W[d*128 + col];
    __syncthreads();
    up2[hf][col] = a;
  }
  __syncthreads();
  if (t < 128) su[t] = up2[0][t] + up2[1][t];
  __syncthreads();
  {  // GRU gemv: all 256 threads, 3 columns each over combined WgT[128][768]
    float a0 = b_ih[t];
    float a1 = (t < 128) ? b_ih[256+t] : b_hh[t-128];
    float a2 = b_hh[t+128];
    const float* v1p = (t < 128) ? su : hb;
    for (int d = 0; d < 128; d++) {
      float sd = su[d], hd = hb[d], vd = v1p[d];
      const float* wr = WgT + d*768 + t;
      a0 += sd * wr[0];
      a1 += vd * wr[256];
      a2 += hd * wr[512];
    }
    gg[t] = a0; gg[t+256] = a1; gg[t+512] = a2;
  }
  __syncthreads();
  if (t < 128) {                       // GRU gates
    float r = sigmf(gg[t] + gg[384+t]);
    float z = sigmf(gg[128+t] + gg[512+t]);
    float n = tanhf(gg[256+t] + r * gg[640+t]);
    s1[t] = (1.f - z)*n + z*hb[t];
  }
  __syncthreads();
  if (t < 64) {                        // LN(s1) stats (g_mlp)
    float a = s1[t], b = s1[t+64];
    float s = a + b, s2 = a*a + b*b;
    #pragma unroll
    for (int st = 1; st < 64; st <<= 1) { s += __shfl_xor(s, st); s2 += __shfl_xor(s2, st); }
    if (t == 0) { float mean = s*(1.f/128.f); stats[0] = mean;
                  stats[1] = rsqrtf(s2*(1.f/128.f) - mean*mean + LNEPS); }
  }
  __syncthreads();
  if (t < 128) smv[t] = (s1[t] - stats[0])*stats[1]*g_mlp[t] + b_mlp[t];
  __syncthreads();
  {  // h = relu(W1 smv + b1) -- split gemv
    float a = hf ? 0.f : b1[col];
    const float* W = W1T + hf*64*128;
    const float* v = smv + hf*64;
    #pragma unroll 8
    for (int d = 0; d < 64; d++) a += v[d] * W[d*128 + col];
    up2[hf][col] = a;
  }
  __syncthreads();
  if (t < 128) hmv[t] = fmaxf(up2[0][t] + up2[1][t], 0.f);
  __syncthreads();
  {  // s2 = s1 + W2 h + b2 -- split gemv
    float a = 0.f;
    const float* W = W2T + hf*64*128;
    const float* v = hmv + hf*64;
    #pragma unroll 8
    for (int d = 0; d < 64; d++) a += v[d] * W[d*128 + col];
    up2[hf][col] = a;
  }
  __syncthreads();
  if (t < 128) {
    float a = s1[t] + b2[t] + up2[0][t] + up2[1][t];
    s2v[t] = a;
    slots_out[row*128 + t] = a;
  }
  __syncthreads();
  if (t < 64) {                        // LN(new slots) stats (g_slot) for next q
    float a = s2v[t], b = s2v[t+64];
    float s = a + b, s2 = a*a + b*b;
    #pragma unroll
    for (int st = 1; st < 64; st <<= 1) { s += __shfl_xor(s, st); s2 += __shfl_xor(s2, st); }
    if (t == 0) { float mean = s*(1.f/128.f); stats[0] = mean;
                  stats[1] = rsqrtf(s2*(1.f/128.f) - mean*mean + LNEPS); }
  }
  __syncthreads();
  if (t < 128) sqv[t] = (s2v[t] - stats[0])*stats[1]*g_slot[t] + b_slot[t];
  __syncthreads();
  {  // qa = Wq sqv + bq -- split gemv
    float a = hf ? 0.f : bq[col];
    const float* W = WqT + hf*64*128;
    const float* v = sqv + hf*64;
    #pragma unroll 8
    for (int d = 0; d < 64; d++) a += v[d] * W[d*128 + col];
    up2[hf][col] = a;
  }
  __syncthreads();
  if (t < 128) qa[t] = up2[0][t] + up2[1][t];
  __syncthreads();
  {  // q~ = scale * Wk^T qa -- split gemv
    float a = 0.f;
    const float* W = Wk + hf*64*128;
    const float* v = qa + hf*64;
    #pragma unroll 8
    for (int j = 0; j < 64; j++) a += v[j] * W[j*128 + col];
    up2[hf][col] = a;
  }
  __syncthreads();
  if (t < 128) qt[row*128 + t] = (up2[0][t] + up2[1][t]) * SCALE;
  if (t < 64) {
    float c = qa[t]*bk[t] + qa[t+64]*bk[t+64];
    #pragma unroll
    for (int st = 1; st < 64; st <<= 1) c += __shfl_xor(c, st);
    if (t == 0) qc[row] = c * SCALE;
  }
}

extern "C" void kernel_launch(void* const* d_in, const int* in_sizes, int n_in,
                              void* d_out, int out_size, void* d_ws, size_t ws_size,
                              hipStream_t stream) {
  const float* x          = (const float*)d_in[0];
  const float* slots_init = (const float*)d_in[1];
  const float* Wq   = (const float*)d_in[2];
  const float* bq   = (const float*)d_in[3];
  const float* Wk   = (const float*)d_in[4];
  const float* bk   = (const float*)d_in[5];
  const float* Wv   = (const float*)d_in[6];
  const float* bv   = (const float*)d_in[7];
  const float* g_in = (const float*)d_in[8];
  const float* b_in = (const float*)d_in[9];
  const float* g_slot = (const float*)d_in[10];
  const float* b_slot = (const float*)d_in[11];
  const float* g_mlp  = (const float*)d_in[12];
  const float* b_mlp  = (const float*)d_in[13];
  const float* W1   = (const float*)d_in[14];
  const float* b1   = (const float*)d_in[15];
  const float* W2   = (const float*)d_in[16];
  const float* b2   = (const float*)d_in[17];
  const float* Wih  = (const float*)d_in[18];
  const float* Whh  = (const float*)d_in[19];
  const float* b_ih = (const float*)d_in[20];
  const float* b_hh = (const float*)d_in[21];

  char* p = (char*)d_ws;
  unsigned short* xn = (unsigned short*)p; p += (size_t)B_*N_*128*2;   // 64 MB bf16
  float* qt    = (float*)p; p += (size_t)B_*KS*128*4;
  float* qc    = (float*)p; p += (size_t)B_*KS*4 + 2048;               // pad
  float* slots = (float*)p; p += (size_t)B_*KS*128*4;
  float* Upart = (float*)p; p += (size_t)B_*NCH*KS*128*4;              // 8 MB
  float* Spart = (float*)p; p += (size_t)B_*NCH*KS*4 + 2048;
  float* WgT   = (float*)p; p += 98304*4;
  float* WqT   = (float*)p; p += 16384*4;
  float* WvT   = (float*)p; p += 16384*4;
  float* W1T   = (float*)p; p += 16384*4;
  float* W2T   = (float*)p; p += 16384*4;

  // one launch: weight prep + q_init + LN(x)->xn (independent branches)
  prep_all<<<3200, 256, 0, stream>>>(Wih, Whh, Wq, Wv, W1, W2,
      WgT, WqT, WvT, W1T, W2T,
      slots_init, g_slot, b_slot, bq, Wk, bk, qt, qc,
      x, g_in, b_in, xn);

  // iteration 0
  attn_kernel<<<dim3(NCH, B_), 256, 0, stream>>>(xn, qt, qc, Upart, Spart);
  update_kernel<<<512, 256, 0, stream>>>(slots_init, slots, Upart, Spart,
      WvT, bv, WgT, b_ih, b_hh, g_mlp, b_mlp, W1T, b1, W2T, b2,
      g_slot, b_slot, WqT, bq, Wk, bk, qt, qc);

  // iteration 1
  attn_kernel<<<dim3(NCH, B_), 256, 0, stream>>>(xn, qt, qc, Upart, Spart);
  update_kernel<<<512, 256, 0, stream>>>(slots, slots, Upart, Spart,
      WvT, bv, WgT, b_ih, b_hh, g_mlp, b_mlp, W1T, b1, W2T, b2,
      g_slot, b_slot, WqT, bq, Wk, bk, qt, qc);

  // iteration 2 (writes d_out)
  attn_kernel<<<dim3(NCH, B_), 256, 0, stream>>>(xn, qt, qc, Upart, Spart);
  update_kernel<<<512, 256, 0, stream>>>(slots, (float*)d_out, Upart, Spart,
      WvT, bv, WgT, b_ih, b_hh, g_mlp, b_mlp, W1T, b1, W2T, b2,
      g_slot, b_slot, WqT, bq, Wk, bk, qt, qc);

  (void)in_sizes; (void)n_in; (void)out_size; (void)ws_size;
}

// Round 6
// 372.039 us; speedup vs baseline: 1.0639x; 1.0132x over previous
//
#include <hip/hip_runtime.h>
#include <hip/hip_bf16.h>

#define B_ 64
#define N_ 4096
#define KS 8
#define NCH 16          // token chunks (blocks) per batch for attention
#define NG 4            // 16-token groups per wave (tokens/block = 4*NG*16 = 256)
#define TP 136          // padded LDS tile row, bf16 elems (272B row, 16B-aligned)
#define LNEPS 1e-5f
#define EPSA 1e-8f
#define SCALE 0.08838834764831845f   // 1/sqrt(128)

typedef short short8  __attribute__((ext_vector_type(8)));
typedef short short4v __attribute__((ext_vector_type(4)));
typedef float f32x4   __attribute__((ext_vector_type(4)));
typedef float f32x2   __attribute__((ext_vector_type(2)));

__device__ __forceinline__ unsigned short f2bf(float f) {
  union { float f; unsigned u; } v; v.f = f;
  unsigned r = v.u + 0x7fffu + ((v.u >> 16) & 1u);   // RNE
  return (unsigned short)(r >> 16);
}
__device__ __forceinline__ float bflo(unsigned u) {
  union { unsigned u; float f; } c; c.u = u << 16; return c.f;
}
__device__ __forceinline__ float bfhi(unsigned u) {
  union { unsigned u; float f; } c; c.u = u & 0xffff0000u; return c.f;
}
__device__ __forceinline__ float sigmf(float x) { return 1.f / (1.f + __expf(-x)); }

// packed fp32 FMA: d.lo += f.lo*p, d.hi += f.hi*p, p broadcast from a pair's
// lo or hi word via VOP3P op_sel (CDNA4 v_pk_fma_f32 = the 2x fp32 rate path).
__device__ __forceinline__ void pkfma_lo(f32x2 &d, f32x2 f, f32x2 p2) {
  asm("v_pk_fma_f32 %0, %1, %2, %0 op_sel_hi:[1,0,1]" : "+v"(d) : "v"(f), "v"(p2));
}
__device__ __forceinline__ void pkfma_hi(f32x2 &d, f32x2 f, f32x2 p2) {
  asm("v_pk_fma_f32 %0, %1, %2, %0 op_sel:[0,1,0] op_sel_hi:[1,1,1]" : "+v"(d) : "v"(f), "v"(p2));
}

// ---------------- fused prep: weight transposes + q_init + LN(x)->xn ----------------
__global__ __launch_bounds__(256) void prep_all(
    const float* __restrict__ Wih, const float* __restrict__ Whh,
    const float* __restrict__ Wq,  const float* __restrict__ Wv,
    const float* __restrict__ W1,  const float* __restrict__ W2,
    float* __restrict__ WgT, float* __restrict__ WqT,
    float* __restrict__ WvT, float* __restrict__ W1T, float* __restrict__ W2T,
    const float* __restrict__ slots_in, const float* __restrict__ g_slot, const float* __restrict__ b_slot,
    const float* __restrict__ bq,
    const float* __restrict__ Wk, const float* __restrict__ bk,
    float* __restrict__ qt, float* __restrict__ qc,
    const float* __restrict__ x, const float* __restrict__ g_in, const float* __restrict__ b_in,
    unsigned short* __restrict__ xn)
{
  __shared__ float sarr[128];
  __shared__ float qarr[128];
  const int bb = blockIdx.x, t = threadIdx.x;

  if (bb < 640) {
    int id = bb * 256 + t;
    if (id < 98304) {
      int d = id / 768, j = id % 768;
      WgT[id] = (j < 384) ? Wih[j*128 + d] : Whh[(j-384)*128 + d];
    } else if (id < 114688) {
      int k = id - 98304; WqT[k] = Wq[(k % 128) * 128 + k / 128];
    } else if (id < 131072) {
      int k = id - 114688; WvT[k] = Wv[(k % 128) * 128 + k / 128];
    } else if (id < 147456) {
      int k = id - 131072; W1T[k] = W1[(k % 128) * 128 + k / 128];
    } else if (id < 163840) {
      int k = id - 147456; W2T[k] = W2[(k % 128) * 128 + k / 128];
    }
    return;
  }

  if (bb < 1152) {
    int row = bb - 640;
    if (t < 64) {
      float a = slots_in[row*128 + t], b = slots_in[row*128 + 64 + t];
      float s = a + b, s2 = a*a + b*b;
      #pragma unroll
      for (int st = 1; st < 64; st <<= 1) { s += __shfl_xor(s, st); s2 += __shfl_xor(s2, st); }
      float mean = s * (1.f/128.f);
      float rstd = rsqrtf(s2 * (1.f/128.f) - mean*mean + LNEPS);
      sarr[t]    = (a - mean) * rstd * g_slot[t]    + b_slot[t];
      sarr[t+64] = (b - mean) * rstd * g_slot[t+64] + b_slot[t+64];
    }
    __syncthreads();
    if (t < 128) {                        // q = Wq s + bq  (raw Wq row-dot)
      float a = bq[t];
      for (int d = 0; d < 128; d++) a += sarr[d] * Wq[t*128 + d];
      qarr[t] = a;
    }
    __syncthreads();
    if (t < 128) {
      float a = 0.f;
      for (int j = 0; j < 128; j++) a += qarr[j] * Wk[j*128 + t];
      qt[row*128 + t] = a * SCALE;
    }
    if (t < 64) {
      float c = qarr[t]*bk[t] + qarr[t+64]*bk[t+64];
      #pragma unroll
      for (int st = 1; st < 64; st <<= 1) c += __shfl_xor(c, st);
      if (t == 0) qc[row] = c * SCALE;
    }
    return;
  }

  {  // LN: 32 lanes/row, 4 floats/lane; block handles 128 rows
    const int w = t >> 6, lane = t & 63;
    const int half = lane >> 5, sl = lane & 31;
    const size_t row0 = (size_t)(bb - 1152) * 128 + w * 32 + half;
    float4 gg = *(const float4*)(g_in + sl*4);
    float4 bv4 = *(const float4*)(b_in + sl*4);
    for (int i = 0; i < 16; i++) {
      size_t row = row0 + i*2;
      float4 v = *(const float4*)(x + row*128 + sl*4);
      float s  = v.x + v.y + v.z + v.w;
      float s2 = v.x*v.x + v.y*v.y + v.z*v.z + v.w*v.w;
      #pragma unroll
      for (int st = 1; st < 32; st <<= 1) { s += __shfl_xor(s, st); s2 += __shfl_xor(s2, st); }
      float mean = s * (1.f/128.f);
      float rstd = rsqrtf(s2*(1.f/128.f) - mean*mean + LNEPS);
      unsigned short h0 = f2bf((v.x - mean)*rstd*gg.x + bv4.x);
      unsigned short h1 = f2bf((v.y - mean)*rstd*gg.y + bv4.y);
      unsigned short h2 = f2bf((v.z - mean)*rstd*gg.z + bv4.z);
      unsigned short h3 = f2bf((v.w - mean)*rstd*gg.w + bv4.w);
      uint2 pk;
      pk.x = (unsigned)h0 | ((unsigned)h1 << 16);
      pk.y = (unsigned)h2 | ((unsigned)h3 << 16);
      *(uint2*)(xn + row*128 + sl*4) = pk;
    }
  }
}

// ---------------- attention sweep (xn bf16 input) ----------------
// grid (NCH=16, B_), 256 threads = 4 waves, 64 tokens/wave as NG=4 groups of
// 16, register-double-buffered: group g+1's 4 global loads are issued before
// group g's compute so HBM latency hides under MFMA+softmax+U-pass.
// S lane-reduce deferred out of the group loop (linear => same result).
__global__ __launch_bounds__(256) void attn_kernel(
    const unsigned short* __restrict__ xn,
    const float* __restrict__ qt, const float* __restrict__ qc,
    float* __restrict__ Upart, float* __restrict__ Spart)
{
  __shared__ union ShMem {
    unsigned short xt[4][16][TP];   // 17408 B (per-group tile, reused)
    float ured[4][8][128];          // 16384 B
  } sh;
  __shared__ __align__(16) float pb[4][16][8];
  __shared__ float sred[4][8];

  const int tid = threadIdx.x;
  const int w = tid >> 6, lane = tid & 63;
  const int chunk = blockIdx.x, batch = blockIdx.y;
  const int m = lane & 15, quad = lane >> 4;

  // A-fragments: q~ rows (slot = m), zeros for m>=8. A[m][k], k=quad*8+j (+32*kc)
  short8 afrag[4];
  if (m < KS) {
    const float* qp = qt + (batch*KS + m)*128 + quad*8;
    #pragma unroll
    for (int kc = 0; kc < 4; kc++) {
      short8 a;
      #pragma unroll
      for (int j = 0; j < 8; j++) a[j] = (short)f2bf(qp[kc*32 + j]);
      afrag[kc] = a;
    }
  } else {
    #pragma unroll
    for (int kc = 0; kc < 4; kc++) {
      short8 a;
      #pragma unroll
      for (int j = 0; j < 8; j++) a[j] = 0;
      afrag[kc] = a;
    }
  }
  float creg[4];
  #pragma unroll
  for (int r = 0; r < 4; r++) creg[r] = qc[batch*KS + ((quad*4 + r) & 7)];

  const int tb = (chunk*4 + w) * (NG*16);
  const unsigned short* xpb = xn + (size_t)(batch*N_ + tb + m)*128 + quad*8;

  // prologue: load group 0 into b0
  short8 b0[4], b1[4];
  #pragma unroll
  for (int kc = 0; kc < 4; kc++) b0[kc] = *(const short8*)(xpb + kc*32);

  // U~ accumulators: lane owns dims 2*lane, 2*lane+1 as one packed pair
  f32x2 u01[8];
  #pragma unroll
  for (int i = 0; i < 8; i++) { u01[i].x = 0.f; u01[i].y = 0.f; }
  float sAcc[4] = {0.f, 0.f, 0.f, 0.f};

  #pragma unroll
  for (int g = 0; g < NG; g++) {
    short8* bc = (g & 1) ? b1 : b0;
    short8* bn = (g & 1) ? b0 : b1;

    // prefetch next group's fragments (issued before any use of bc's LDS copy)
    if (g + 1 < NG) {
      const unsigned short* xq = xpb + (size_t)(g + 1) * 16 * 128;
      #pragma unroll
      for (int kc = 0; kc < 4; kc++) bn[kc] = *(const short8*)(xq + kc*32);
    }

    // stage this group's tile in LDS (per-wave region, wave-ordered vs reads)
    #pragma unroll
    for (int kc = 0; kc < 4; kc++)
      *(short8*)&sh.xt[w][m][kc*32 + quad*8] = bc[kc];

    // logits = q~ . xn + c   (D: row=slot(quad*4+r), col=token m)
    f32x4 acc = {0.f, 0.f, 0.f, 0.f};
    #pragma unroll
    for (int kc = 0; kc < 4; kc++)
      acc = __builtin_amdgcn_mfma_f32_16x16x32_bf16(afrag[kc], bc[kc], acc, 0, 0, 0);
    float l[4], o[4];
    #pragma unroll
    for (int r = 0; r < 4; r++) l[r] = acc[r] + creg[r];
    #pragma unroll
    for (int r = 0; r < 4; r++) o[r] = __shfl_xor(l[r], 16);   // swap slot halves
    float mx = fmaxf(fmaxf(fmaxf(l[0], l[1]), fmaxf(l[2], l[3])),
                     fmaxf(fmaxf(o[0], o[1]), fmaxf(o[2], o[3])));
    float e0 = __expf(l[0]-mx), e1 = __expf(l[1]-mx), e2 = __expf(l[2]-mx), e3 = __expf(l[3]-mx);
    float den = e0+e1+e2+e3 + __expf(o[0]-mx)+__expf(o[1]-mx)+__expf(o[2]-mx)+__expf(o[3]-mx);
    float rd = 1.f / den;
    float p0 = e0*rd + EPSA, p1 = e1*rd + EPSA, p2 = e2*rd + EPSA, p3 = e3*rd + EPSA;
    if (lane < 32) {   // quads 0/1 hold real slots 0-3 / 4-7 for token m
      float4 pv; pv.x = p0; pv.y = p1; pv.z = p2; pv.w = p3;
      *(float4*)&pb[w][m][quad*4] = pv;
    }

    // U~ accumulate over this group's 16 tokens (packed fp32 FMA)
    #pragma unroll
    for (int t = 0; t < 16; t++) {
      f32x2 pA01 = *(const f32x2*)&pb[w][t][0];
      f32x2 pA23 = *(const f32x2*)&pb[w][t][2];
      f32x2 pB01 = *(const f32x2*)&pb[w][t][4];
      f32x2 pB23 = *(const f32x2*)&pb[w][t][6];
      unsigned vp = *(const unsigned*)&sh.xt[w][t][lane*2];
      f32x2 f; f.x = bflo(vp); f.y = bfhi(vp);
      pkfma_lo(u01[0], f, pA01); pkfma_hi(u01[1], f, pA01);
      pkfma_lo(u01[2], f, pA23); pkfma_hi(u01[3], f, pA23);
      pkfma_lo(u01[4], f, pB01); pkfma_hi(u01[5], f, pB01);
      pkfma_lo(u01[6], f, pB23); pkfma_hi(u01[7], f, pB23);
    }

    // defer the 16-lane S reduce: just accumulate per-lane p sums (linear)
    sAcc[0] += p0; sAcc[1] += p1; sAcc[2] += p2; sAcc[3] += p3;
  }

  // single S lane-reduce over the 16 token-lanes in each quad-pair
  #pragma unroll
  for (int st = 1; st < 16; st <<= 1) {
    #pragma unroll
    for (int r = 0; r < 4; r++) sAcc[r] += __shfl_xor(sAcc[r], st);
  }
  if (lane == 0)  { sred[w][0]=sAcc[0]; sred[w][1]=sAcc[1]; sred[w][2]=sAcc[2]; sred[w][3]=sAcc[3]; }
  if (lane == 16) { sred[w][4]=sAcc[0]; sred[w][5]=sAcc[1]; sred[w][6]=sAcc[2]; sred[w][7]=sAcc[3]; }

  __syncthreads();                       // xt dead everywhere -> reuse as ured
  #pragma unroll
  for (int i = 0; i < 8; i++)
    *(f32x2*)&sh.ured[w][i][lane*2] = u01[i];
  __syncthreads();

  {
    const float* ur = &sh.ured[0][0][0];
    int i4 = tid * 4;
    float4 a = *(const float4*)(ur + i4);
    float4 b = *(const float4*)(ur + 1024 + i4);
    float4 c = *(const float4*)(ur + 2048 + i4);
    float4 d = *(const float4*)(ur + 3072 + i4);
    float4 o4;
    o4.x = a.x+b.x+c.x+d.x; o4.y = a.y+b.y+c.y+d.y;
    o4.z = a.z+b.z+c.z+d.z; o4.w = a.w+b.w+c.w+d.w;
    *(float4*)(Upart + (size_t)(batch*NCH + chunk)*1024 + i4) = o4;
    if (tid < 8)
      Spart[(batch*NCH + chunk)*8 + tid] =
        sred[0][tid] + sred[1][tid] + sred[2][tid] + sred[3][tid];
  }
}

// ---------------- per-slot-row update: Wv-apply + GRU + MLP + next q~ ----------------
__global__ __launch_bounds__(256) void update_kernel(
    const float* __restrict__ slots_in, float* __restrict__ slots_out,
    const float* __restrict__ Upart, const float* __restrict__ Spart,
    const float* __restrict__ WvT, const float* __restrict__ bv,
    const float* __restrict__ WgT,
    const float* __restrict__ b_ih, const float* __restrict__ b_hh,
    const float* __restrict__ g_mlp, const float* __restrict__ b_mlp,
    const float* __restrict__ W1T, const float* __restrict__ b1,
    const float* __restrict__ W2T, const float* __restrict__ b2,
    const float* __restrict__ g_slot, const float* __restrict__ b_slot,
    const float* __restrict__ WqT, const float* __restrict__ bq,
    const float* __restrict__ Wk, const float* __restrict__ bk,
    float* __restrict__ qt, float* __restrict__ qc)
{
  __shared__ float bu[128], su[128], hb[128];
  __shared__ float gg[768];
  __shared__ float s1[128], smv[128], hmv[128], s2v[128], sqv[128], qa[128];
  __shared__ float up2[2][128];
  __shared__ float stats[2], sSum;
  int row = blockIdx.x, t = threadIdx.x;
  int batch = row >> 3, slot = row & 7;
  const int col = t & 127, hf = t >> 7;

  {  // Upart reduce split over all 256 threads (2 halves of the 16 chunks)
    const float* Up = Upart + ((size_t)(batch*NCH + hf*8)*8 + slot)*128 + col;
    float ua = 0.f;
    #pragma unroll
    for (int c = 0; c < 8; c++) ua += Up[(size_t)c*1024];
    up2[hf][col] = ua;
  }
  if (t < NCH) {
    float sv = Spart[(batch*NCH + t)*8 + slot];
    #pragma unroll
    for (int st = 1; st < NCH; st <<= 1) sv += __shfl_xor(sv, st);
    if (t == 0) sSum = sv;
  }
  if (t >= 64 && t < 192) hb[t-64] = slots_in[row*128 + (t-64)];
  __syncthreads();
  if (t < 128) bu[t] = (up2[0][t] + up2[1][t]) / sSum;
  __syncthreads();
  {  // updates = Wv (U~/S) + bv  -- split gemv
    float a = hf ? 0.f : bv[col];
    const float* W = WvT + hf*64*128;
    const float* v = bu + hf*64;
    #pragma unroll 8
    for (int d = 0; d < 64; d++) a += v[d] * W[d*128 + col];
    __syncthreads();
    up2[hf][col] = a;
  }
  __syncthreads();
  if (t < 128) su[t] = up2[0][t] + up2[1][t];
  __syncthreads();
  {  // GRU gemv: all 256 threads, 3 columns each over combined WgT[128][768]
    float a0 = b_ih[t];
    float a1 = (t < 128) ? b_ih[256+t] : b_hh[t-128];
    float a2 = b_hh[t+128];
    const float* v1p = (t < 128) ? su : hb;
    for (int d = 0; d < 128; d++) {
      float sd = su[d], hd = hb[d], vd = v1p[d];
      const float* wr = WgT + d*768 + t;
      a0 += sd * wr[0];
      a1 += vd * wr[256];
      a2 += hd * wr[512];
    }
    gg[t] = a0; gg[t+256] = a1; gg[t+512] = a2;
  }
  __syncthreads();
  if (t < 128) {                       // GRU gates
    float r = sigmf(gg[t] + gg[384+t]);
    float z = sigmf(gg[128+t] + gg[512+t]);
    float n = tanhf(gg[256+t] + r * gg[640+t]);
    s1[t] = (1.f - z)*n + z*hb[t];
  }
  __syncthreads();
  if (t < 64) {                        // LN(s1) stats (g_mlp)
    float a = s1[t], b = s1[t+64];
    float s = a + b, s2 = a*a + b*b;
    #pragma unroll
    for (int st = 1; st < 64; st <<= 1) { s += __shfl_xor(s, st); s2 += __shfl_xor(s2, st); }
    if (t == 0) { float mean = s*(1.f/128.f); stats[0] = mean;
                  stats[1] = rsqrtf(s2*(1.f/128.f) - mean*mean + LNEPS); }
  }
  __syncthreads();
  if (t < 128) smv[t] = (s1[t] - stats[0])*stats[1]*g_mlp[t] + b_mlp[t];
  __syncthreads();
  {  // h = relu(W1 smv + b1) -- split gemv
    float a = hf ? 0.f : b1[col];
    const float* W = W1T + hf*64*128;
    const float* v = smv + hf*64;
    #pragma unroll 8
    for (int d = 0; d < 64; d++) a += v[d] * W[d*128 + col];
    up2[hf][col] = a;
  }
  __syncthreads();
  if (t < 128) hmv[t] = fmaxf(up2[0][t] + up2[1][t], 0.f);
  __syncthreads();
  {  // s2 = s1 + W2 h + b2 -- split gemv
    float a = 0.f;
    const float* W = W2T + hf*64*128;
    const float* v = hmv + hf*64;
    #pragma unroll 8
    for (int d = 0; d < 64; d++) a += v[d] * W[d*128 + col];
    up2[hf][col] = a;
  }
  __syncthreads();
  if (t < 128) {
    float a = s1[t] + b2[t] + up2[0][t] + up2[1][t];
    s2v[t] = a;
    slots_out[row*128 + t] = a;
  }
  __syncthreads();
  if (t < 64) {                        // LN(new slots) stats (g_slot) for next q
    float a = s2v[t], b = s2v[t+64];
    float s = a + b, s2 = a*a + b*b;
    #pragma unroll
    for (int st = 1; st < 64; st <<= 1) { s += __shfl_xor(s, st); s2 += __shfl_xor(s2, st); }
    if (t == 0) { float mean = s*(1.f/128.f); stats[0] = mean;
                  stats[1] = rsqrtf(s2*(1.f/128.f) - mean*mean + LNEPS); }
  }
  __syncthreads();
  if (t < 128) sqv[t] = (s2v[t] - stats[0])*stats[1]*g_slot[t] + b_slot[t];
  __syncthreads();
  {  // qa = Wq sqv + bq -- split gemv
    float a = hf ? 0.f : bq[col];
    const float* W = WqT + hf*64*128;
    const float* v = sqv + hf*64;
    #pragma unroll 8
    for (int d = 0; d < 64; d++) a += v[d] * W[d*128 + col];
    up2[hf][col] = a;
  }
  __syncthreads();
  if (t < 128) qa[t] = up2[0][t] + up2[1][t];
  __syncthreads();
  {  // q~ = scale * Wk^T qa -- split gemv
    float a = 0.f;
    const float* W = Wk + hf*64*128;
    const float* v = qa + hf*64;
    #pragma unroll 8
    for (int j = 0; j < 64; j++) a += v[j] * W[j*128 + col];
    up2[hf][col] = a;
  }
  __syncthreads();
  if (t < 128) qt[row*128 + t] = (up2[0][t] + up2[1][t]) * SCALE;
  if (t < 64) {
    float c = qa[t]*bk[t] + qa[t+64]*bk[t+64];
    #pragma unroll
    for (int st = 1; st < 64; st <<= 1) c += __shfl_xor(c, st);
    if (t == 0) qc[row] = c * SCALE;
  }
}

extern "C" void kernel_launch(void* const* d_in, const int* in_sizes, int n_in,
                              void* d_out, int out_size, void* d_ws, size_t ws_size,
                              hipStream_t stream) {
  const float* x          = (const float*)d_in[0];
  const float* slots_init = (const float*)d_in[1];
  const float* Wq   = (const float*)d_in[2];
  const float* bq   = (const float*)d_in[3];
  const float* Wk   = (const float*)d_in[4];
  const float* bk   = (const float*)d_in[5];
  const float* Wv   = (const float*)d_in[6];
  const float* bv   = (const float*)d_in[7];
  const float* g_in = (const float*)d_in[8];
  const float* b_in = (const float*)d_in[9];
  const float* g_slot = (const float*)d_in[10];
  const float* b_slot = (const float*)d_in[11];
  const float* g_mlp  = (const float*)d_in[12];
  const float* b_mlp  = (const float*)d_in[13];
  const float* W1   = (const float*)d_in[14];
  const float* b1   = (const float*)d_in[15];
  const float* W2   = (const float*)d_in[16];
  const float* b2   = (const float*)d_in[17];
  const float* Wih  = (const float*)d_in[18];
  const float* Whh  = (const float*)d_in[19];
  const float* b_ih = (const float*)d_in[20];
  const float* b_hh = (const float*)d_in[21];

  char* p = (char*)d_ws;
  unsigned short* xn = (unsigned short*)p; p += (size_t)B_*N_*128*2;   // 64 MB bf16
  float* qt    = (float*)p; p += (size_t)B_*KS*128*4;
  float* qc    = (float*)p; p += (size_t)B_*KS*4 + 2048;               // pad
  float* slots = (float*)p; p += (size_t)B_*KS*128*4;
  float* Upart = (float*)p; p += (size_t)B_*NCH*KS*128*4;              // 4 MB
  float* Spart = (float*)p; p += (size_t)B_*NCH*KS*4 + 2048;
  float* WgT   = (float*)p; p += 98304*4;
  float* WqT   = (float*)p; p += 16384*4;
  float* WvT   = (float*)p; p += 16384*4;
  float* W1T   = (float*)p; p += 16384*4;
  float* W2T   = (float*)p; p += 16384*4;

  // one launch: weight prep + q_init + LN(x)->xn (independent branches)
  prep_all<<<3200, 256, 0, stream>>>(Wih, Whh, Wq, Wv, W1, W2,
      WgT, WqT, WvT, W1T, W2T,
      slots_init, g_slot, b_slot, bq, Wk, bk, qt, qc,
      x, g_in, b_in, xn);

  // iteration 0
  attn_kernel<<<dim3(NCH, B_), 256, 0, stream>>>(xn, qt, qc, Upart, Spart);
  update_kernel<<<512, 256, 0, stream>>>(slots_init, slots, Upart, Spart,
      WvT, bv, WgT, b_ih, b_hh, g_mlp, b_mlp, W1T, b1, W2T, b2,
      g_slot, b_slot, WqT, bq, Wk, bk, qt, qc);

  // iteration 1
  attn_kernel<<<dim3(NCH, B_), 256, 0, stream>>>(xn, qt, qc, Upart, Spart);
  update_kernel<<<512, 256, 0, stream>>>(slots, slots, Upart, Spart,
      WvT, bv, WgT, b_ih, b_hh, g_mlp, b_mlp, W1T, b1, W2T, b2,
      g_slot, b_slot, WqT, bq, Wk, bk, qt, qc);

  // iteration 2 (writes d_out)
  attn_kernel<<<dim3(NCH, B_), 256, 0, stream>>>(xn, qt, qc, Upart, Spart);
  update_kernel<<<512, 256, 0, stream>>>(slots, (float*)d_out, Upart, Spart,
      WvT, bv, WgT, b_ih, b_hh, g_mlp, b_mlp, W1T, b1, W2T, b2,
      g_slot, b_slot, WqT, bq, Wk, bk, qt, qc);

  (void)in_sizes; (void)n_in; (void)out_size; (void)ws_size;
}